// Round 1
// 7462.966 us; speedup vs baseline: 1.0483x; 1.0483x over previous
//
#include <hip/hip_runtime.h>
#include <hip/hip_bf16.h>
#include <math.h>

#define BATCH 64
#define DM 768
#define NHD 12
#define NLAYER 8
#define NLOC 49
#define NSC 256
#define ATT_SCALE 0.125f
#define QT 32
#define ML (BATCH * NLOC)      // 3136
#define ML_PAD 3200            // 25 * 128
#define MS (BATCH * NSC)       // 16384

typedef short bf16x8 __attribute__((ext_vector_type(8)));
typedef float f32x4 __attribute__((ext_vector_type(4)));

__device__ __forceinline__ float bf2f(unsigned short r) {
  return __uint_as_float(((unsigned)r) << 16);
}
__device__ __forceinline__ unsigned short f2bf(float x) {
  __hip_bfloat16 h = __float2bfloat16(x);
  unsigned short r;
  __builtin_memcpy(&r, &h, 2);
  return r;
}

// ------------------------------------------------------------------
// rope tables (fp32)
// ------------------------------------------------------------------
__global__ void rope_local_k(const float* __restrict__ centers, const float* __restrict__ scales,
                             const float* __restrict__ periods, float* __restrict__ lcos,
                             float* __restrict__ lsin) {
  int t = blockIdx.x * blockDim.x + threadIdx.x;
  const int total = BATCH * NLOC * 32;
  if (t >= total) return;
  int d = t & 31;
  int r = (t >> 5) % NLOC;
  int b = t / (NLOC * 32);
  int pi = d & 15;
  float gx = ((r % 7) + 0.5f) / 7.0f - 0.5f;
  float gy = ((r / 7) + 0.5f) / 7.0f - 0.5f;
  float coord = (d < 16) ? (centers[b * 2 + 0] + scales[b * 2 + 0] * gx)
                         : (centers[b * 2 + 1] + scales[b * 2 + 1] * gy);
  float ang = 6.283185307179586f * coord / periods[pi];
  lcos[t] = cosf(ang);
  lsin[t] = sinf(ang);
}

__global__ void rope_scene_k(const float* __restrict__ periods, float* __restrict__ scos,
                             float* __restrict__ ssin) {
  int t = blockIdx.x * blockDim.x + threadIdx.x;
  const int total = NSC * 32;
  if (t >= total) return;
  int d = t & 31;
  int r = t >> 5;
  int pi = d & 15;
  float coord = (d < 16) ? ((r % 16) + 0.5f) / 16.0f : ((r / 16) + 0.5f) / 16.0f;
  float ang = 6.283185307179586f * coord / periods[pi];
  scos[t] = cosf(ang);
  ssin[t] = sinf(ang);
}

// ------------------------------------------------------------------
// init: streams (fp32 in d_out) + bf16 mirrors
// ------------------------------------------------------------------
__global__ void init_out_k(const float* __restrict__ local_in, const float* __restrict__ scene_tok,
                           float* __restrict__ out, unsigned short* __restrict__ lbf,
                           unsigned short* __restrict__ sbf) {
  int t = blockIdx.x * blockDim.x + threadIdx.x;
  const int NL = ML * DM;
  const int NS = MS * DM;
  if (t < NL) {
    float v = local_in[t];
    out[t] = v;
    lbf[t] = f2bf(v);
  } else if (t < NL + NS) {
    float v = scene_tok[(t - NL) % (NSC * DM)];
    out[t] = v;
    sbf[t - NL] = f2bf(v);
  }
}

// ------------------------------------------------------------------
// per-layer weight convert + transpose: fp32 [K,N] -> bf16 [N,K]
// 12 matrices, fixed shapes across layers; 32x32 LDS tiles.
// ------------------------------------------------------------------
struct SrcPtrs {
  const float* p[12];
};

// order: qkv, wp, w1, w2, rq, rk, rv, ro, wq, wk, wv, wo
__constant__ const int wc_K[12] = {768, 768, 768, 3072, 768, 768, 768, 768, 768, 768, 768, 768};
__constant__ const int wc_N[12] = {2304, 768, 3072, 768, 768, 768, 768, 768, 768, 768, 768, 768};
__constant__ const int wc_blk[13] = {0,    1728, 2304, 4608, 6912,  7488,  8064,
                                     8640, 9216, 9792, 10368, 10944, 11520};
__constant__ const size_t wc_off[12] = {0,       1769472, 2359296, 4718592,
                                        7077888, 7667712, 8257536, 8847360,
                                        9437184, 10027008, 10616832, 11206656};
#define W_QKV 0
#define W_P 1769472
#define W_1 2359296
#define W_2 4718592
#define W_RQ 7077888
#define W_RK 7667712
#define W_RV 8257536
#define W_RO 8847360
#define W_WQ 9437184
#define W_WK 10027008
#define W_WV 10616832
#define W_WO 11206656

__global__ __launch_bounds__(256) void wconv_k(SrcPtrs sp, unsigned short* __restrict__ dst) {
  int b = blockIdx.x;
  int mi = 0;
  while (b >= wc_blk[mi + 1]) ++mi;
  int lb = b - wc_blk[mi];
  int K = wc_K[mi], N = wc_N[mi];
  int ncol = N >> 5;
  int kt = lb / ncol, nt = lb - kt * ncol;
  const float* src = sp.p[mi];
  __shared__ unsigned short tile[32][33];
  int r = threadIdx.x >> 3, c4 = (threadIdx.x & 7) << 2;
  float4 v = *(const float4*)(src + (size_t)(kt * 32 + r) * N + nt * 32 + c4);
  tile[r][c4 + 0] = f2bf(v.x);
  tile[r][c4 + 1] = f2bf(v.y);
  tile[r][c4 + 2] = f2bf(v.z);
  tile[r][c4 + 3] = f2bf(v.w);
  __syncthreads();
  unsigned short o[4];
  o[0] = tile[c4 + 0][r];
  o[1] = tile[c4 + 1][r];
  o[2] = tile[c4 + 2][r];
  o[3] = tile[c4 + 3][r];
  unsigned short* dp = dst + wc_off[mi] + (size_t)(nt * 32 + r) * K + kt * 32 + c4;
  *(ushort4*)dp = *(const ushort4*)o;
}

// ------------------------------------------------------------------
// bf16 MFMA GEMM: C[M,N] = A[M,K] @ Bt[N,K]^T + bias
// 128x128 tile, BK=64, 256 threads = 4 waves (2x2 of 64x64), 16x16x32 MFMA.
// global_load_lds(16B) staging with XOR chunk swizzle (8 chunks of 16B/row).
// MODE 0: store bf16 Cb. MODE 1: exact GELU, store bf16 Cb.
// MODE 2: Cf = Cf + gate*(acc+bias) (fp32 stream) + bf16 mirror Cb.
// ------------------------------------------------------------------
template <int MODE>
__global__ __launch_bounds__(256) void gemm_mfma(const unsigned short* __restrict__ A,
                                                 const unsigned short* __restrict__ Bt,
                                                 const float* __restrict__ bias,
                                                 unsigned short* __restrict__ Cb,
                                                 float* __restrict__ Cf,
                                                 const float* __restrict__ gate, int M, int N,
                                                 int K) {
  __shared__ unsigned short As[128 * 64];
  __shared__ unsigned short Bs[128 * 64];
  const int tid = threadIdx.x;
  const int w = tid >> 6;
  const int lane = tid & 63;
  const int wm = w & 1, wn = w >> 1;
  const int bm = blockIdx.y << 7;
  const int bn = blockIdx.x << 7;
  const int lrow = lane >> 3;    // 0..7
  const int lchunk = lane & 7;   // dest chunk
  const int schunk = lchunk ^ lrow;  // swizzled source chunk
  const int fm = lane & 15;
  const int quad = lane >> 4;

  f32x4 acc[4][4];
#pragma unroll
  for (int i = 0; i < 4; ++i)
#pragma unroll
    for (int j = 0; j < 4; ++j) acc[i][j] = (f32x4){0.f, 0.f, 0.f, 0.f};

  const size_t a_base = (size_t)(bm + w * 32 + lrow) * K + schunk * 8;
  const size_t b_base = (size_t)(bn + w * 32 + lrow) * K + schunk * 8;

  for (int k0 = 0; k0 < K; k0 += 64) {
    __syncthreads();
#pragma unroll
    for (int q = 0; q < 4; ++q) {
      const unsigned short* ga = A + a_base + (size_t)(q * 8) * K + k0;
      const unsigned short* gb = Bt + b_base + (size_t)(q * 8) * K + k0;
      __builtin_amdgcn_global_load_lds((const __attribute__((address_space(1))) void*)ga,
                                       (__attribute__((address_space(3))) void*)(As + (w * 32 + q * 8) * 64),
                                       16, 0, 0);
      __builtin_amdgcn_global_load_lds((const __attribute__((address_space(1))) void*)gb,
                                       (__attribute__((address_space(3))) void*)(Bs + (w * 32 + q * 8) * 64),
                                       16, 0, 0);
    }
    __syncthreads();
#pragma unroll
    for (int kc = 0; kc < 2; ++kc) {
      bf16x8 af[4], bfr[4];
#pragma unroll
      for (int i = 0; i < 4; ++i) {
        int ra = wm * 64 + i * 16 + fm;
        af[i] = *(const bf16x8*)(As + ra * 64 + (((kc * 4 + quad) ^ (ra & 7)) << 3));
      }
#pragma unroll
      for (int j = 0; j < 4; ++j) {
        int rb = wn * 64 + j * 16 + fm;
        bfr[j] = *(const bf16x8*)(Bs + rb * 64 + (((kc * 4 + quad) ^ (rb & 7)) << 3));
      }
#pragma unroll
      for (int i = 0; i < 4; ++i)
#pragma unroll
        for (int j = 0; j < 4; ++j)
          acc[i][j] = __builtin_amdgcn_mfma_f32_16x16x32_bf16(af[i], bfr[j], acc[i][j], 0, 0, 0);
    }
  }

  // epilogue: lane holds D[quad*4+reg][fm] of each 16x16 tile
#pragma unroll
  for (int j = 0; j < 4; ++j) {
    const int col = bn + wn * 64 + j * 16 + fm;
    const float bj = bias[col];
    float gj = 1.0f;
    if (MODE == 2) gj = gate ? gate[col] : 1.0f;
#pragma unroll
    for (int i = 0; i < 4; ++i) {
#pragma unroll
      for (int reg = 0; reg < 4; ++reg) {
        const int row = bm + wm * 64 + i * 16 + quad * 4 + reg;
        if (row < M) {
          float v = acc[i][j][reg] + bj;
          if (MODE == 1) v = 0.5f * v * (1.0f + erff(v * 0.7071067811865475f));
          const size_t idx = (size_t)row * N + col;
          if (MODE == 2) {
            float o = Cf[idx] + gj * v;
            Cf[idx] = o;
            Cb[idx] = f2bf(o);
          } else {
            Cb[idx] = f2bf(v);
          }
        }
      }
    }
  }
}

// ------------------------------------------------------------------
// LayerNorm over D=768; fp32 in, bf16 out; one wave per row
// ------------------------------------------------------------------
__global__ __launch_bounds__(256) void ln_k(const float* __restrict__ X,
                                            const float* __restrict__ w,
                                            const float* __restrict__ bb,
                                            unsigned short* __restrict__ Y, int rows) {
  const int wid = threadIdx.x >> 6, lane = threadIdx.x & 63;
  const int row = blockIdx.x * 4 + wid;
  if (row >= rows) return;
  const float* x = X + (size_t)row * DM;
  float v[12];
  float s = 0.f;
#pragma unroll
  for (int j = 0; j < 12; ++j) {
    v[j] = x[lane + 64 * j];
    s += v[j];
  }
#pragma unroll
  for (int o = 32; o; o >>= 1) s += __shfl_xor(s, o, 64);
  float mean = s * (1.0f / 768.0f);
  float q = 0.f;
#pragma unroll
  for (int j = 0; j < 12; ++j) {
    float d0 = v[j] - mean;
    q += d0 * d0;
  }
#pragma unroll
  for (int o = 32; o; o >>= 1) q += __shfl_xor(q, o, 64);
  float inv = rsqrtf(q * (1.0f / 768.0f) + 1e-6f);
#pragma unroll
  for (int j = 0; j < 12; ++j) {
    int d0 = lane + 64 * j;
    Y[(size_t)row * DM + d0] = f2bf((v[j] - mean) * inv * w[d0] + bb[d0]);
  }
}

// ------------------------------------------------------------------
// Fused flash attention: MFMA QK^T (bf16), online softmax, VALU PV.
// One (b,h,q-tile-32) per block, 256 threads = 4 waves.
// LDS 21.4 KB (was 58.4 KB): q_s/k_s bf16 chunk-XOR swizzled (gemm scheme),
// 64-key tiles, running (m,l) per row with accumulator rescale.
// ------------------------------------------------------------------
__global__ __launch_bounds__(256) void attn_k(const unsigned short* __restrict__ Q, int qs,
                                              const unsigned short* __restrict__ K, int ks,
                                              const unsigned short* __restrict__ V, int vs,
                                              unsigned short* __restrict__ O,
                                              const float* __restrict__ qcos,
                                              const float* __restrict__ qsin, int qbs,
                                              const float* __restrict__ kcos,
                                              const float* __restrict__ ksin, int kbs, int Nq,
                                              int Nk) {
  __shared__ unsigned short q_s[32 * 64];        // roped Q bf16, swizzled
  __shared__ unsigned short k_s[64 * 64];        // roped K tile bf16, swizzled
  __shared__ __align__(16) float sc[32][68];     // scores -> probs (row stride 272B = 17*16B)
  __shared__ float m_s[32];
  __shared__ float l_s[32];
  __shared__ float rs_s[32];

  const int tid = threadIdx.x;
  const int nQT = (Nq + 31) >> 5;
  const int qt = blockIdx.x % nQT;
  const int h = (blockIdx.x / nQT) % NHD;
  const int b = blockIdx.x / (nQT * NHD);
  const int n0 = qt << 5;
  const int nrows = (Nq - n0 < 32) ? (Nq - n0) : 32;

  const int w = tid >> 6;
  const int lane = tid & 63;
  const int fm = lane & 15;
  const int quad = lane >> 4;

  if (tid < 32) {
    m_s[tid] = -1e30f;
    l_s[tid] = 0.f;
  }

  // stage roped Q as bf16 (zero-pad rows >= nrows)
  for (int idx = tid; idx < 32 * 64; idx += 256) {
    const int r = idx >> 6, d = idx & 63, dd = d & 31;
    unsigned short val = 0;
    if (r < nrows) {
      const int n = n0 + r;
      const size_t base = ((size_t)b * Nq + n) * qs + h * 64;
      const float c = qcos[(size_t)b * qbs + n * 32 + dd];
      const float s = qsin[(size_t)b * qbs + n * 32 + dd];
      const float x1 = bf2f(Q[base + dd]), x2 = bf2f(Q[base + dd + 32]);
      val = f2bf((d < 32) ? (x1 * c - x2 * s) : (x1 * s + x2 * c));
    }
    q_s[(r << 6) + ((((d >> 3) ^ (r & 7)) << 3) | (d & 7))] = val;
  }

  float acc[8] = {0.f, 0.f, 0.f, 0.f, 0.f, 0.f, 0.f, 0.f};

  for (int m0 = 0; m0 < Nk; m0 += 64) {
    const int mc = (Nk - m0 < 64) ? (Nk - m0) : 64;
    __syncthreads();  // prev-tile PV done reading sc; Q/state init done (first iter)

    // stage roped K tile as bf16 (zero-pad rows >= mc)
    for (int idx = tid; idx < 64 * 64; idx += 256) {
      const int r = idx >> 6, d = idx & 63, dd = d & 31;
      unsigned short val = 0;
      if (r < mc) {
        const int m = m0 + r;
        const size_t base = ((size_t)b * Nk + m) * ks + h * 64;
        const float c = kcos[(size_t)b * kbs + m * 32 + dd];
        const float s = ksin[(size_t)b * kbs + m * 32 + dd];
        const float x1 = bf2f(K[base + dd]), x2 = bf2f(K[base + dd + 32]);
        val = f2bf((d < 32) ? (x1 * c - x2 * s) : (x1 * s + x2 * c));
      }
      k_s[(r << 6) + ((((d >> 3) ^ (r & 7)) << 3) | (d & 7))] = val;
    }
    __syncthreads();

    // QK^T via MFMA: wave w -> row-tile (w&1), col-tiles (w>>1)*2 + {0,1}
    {
      const int rt = w & 1;
      const int arow = (rt << 4) + fm;
      const bf16x8 a0 = *(const bf16x8*)(q_s + (arow << 6) + ((quad ^ (arow & 7)) << 3));
      const bf16x8 a1 = *(const bf16x8*)(q_s + (arow << 6) + (((4 + quad) ^ (arow & 7)) << 3));
      const int ct0 = (w >> 1) << 1;
#pragma unroll
      for (int j = 0; j < 2; ++j) {
        const int brow = ((ct0 + j) << 4) + fm;
        const bf16x8 b0 = *(const bf16x8*)(k_s + (brow << 6) + ((quad ^ (brow & 7)) << 3));
        const bf16x8 b1 = *(const bf16x8*)(k_s + (brow << 6) + (((4 + quad) ^ (brow & 7)) << 3));
        f32x4 sv = (f32x4){0.f, 0.f, 0.f, 0.f};
        sv = __builtin_amdgcn_mfma_f32_16x16x32_bf16(a0, b0, sv, 0, 0, 0);
        sv = __builtin_amdgcn_mfma_f32_16x16x32_bf16(a1, b1, sv, 0, 0, 0);
        const int srow = (rt << 4) + (quad << 2);
        const int scol = ((ct0 + j) << 4) + fm;
#pragma unroll
        for (int reg = 0; reg < 4; ++reg) sc[srow + reg][scol] = sv[reg] * ATT_SCALE;
      }
    }
    __syncthreads();

    // online softmax partial update; wave w owns rows [w*8, w*8+8)
#pragma unroll
    for (int rr = 0; rr < 8; ++rr) {
      const int r = (w << 3) + rr;
      const float v = (lane < mc) ? sc[r][lane] : -1e30f;
      float mx = v;
#pragma unroll
      for (int o = 32; o; o >>= 1) mx = fmaxf(mx, __shfl_xor(mx, o, 64));
      const float mo = m_s[r];
      const float mn = fmaxf(mo, mx);
      const float e = (lane < mc) ? __expf(v - mn) : 0.f;
      sc[r][lane] = e;
      float sum = e;
#pragma unroll
      for (int o = 32; o; o >>= 1) sum += __shfl_xor(sum, o, 64);
      if (lane == 0) {
        const float sca = __expf(mo - mn);
        rs_s[r] = sca;
        l_s[r] = l_s[r] * sca + sum;
        m_s[r] = mn;
      }
    }
    __syncthreads();

    // PV accumulate (VALU): col d = lane, rows w + 4*rr
#pragma unroll
    for (int rr = 0; rr < 8; ++rr) acc[rr] *= rs_s[w + (rr << 2)];
    const unsigned short* vp = V + ((size_t)b * Nk + m0) * vs + h * 64 + lane;
    for (int m = 0; m < mc; m += 4) {
      float4 p[8];
#pragma unroll
      for (int rr = 0; rr < 8; ++rr) p[rr] = *(const float4*)&sc[w + (rr << 2)][m];
      const float v0 = bf2f(vp[(size_t)m * vs]);
      const float v1 = (m + 1 < mc) ? bf2f(vp[(size_t)(m + 1) * vs]) : 0.f;
      const float v2 = (m + 2 < mc) ? bf2f(vp[(size_t)(m + 2) * vs]) : 0.f;
      const float v3 = (m + 3 < mc) ? bf2f(vp[(size_t)(m + 3) * vs]) : 0.f;
#pragma unroll
      for (int rr = 0; rr < 8; ++rr) {
        acc[rr] = fmaf(p[rr].x, v0, acc[rr]);
        acc[rr] = fmaf(p[rr].y, v1, acc[rr]);
        acc[rr] = fmaf(p[rr].z, v2, acc[rr]);
        acc[rr] = fmaf(p[rr].w, v3, acc[rr]);
      }
    }
  }

  // epilogue: O = acc / l
#pragma unroll
  for (int rr = 0; rr < 8; ++rr) {
    const int r = w + (rr << 2);
    if (r < nrows)
      O[((size_t)b * Nq + n0 + r) * DM + h * 64 + lane] = f2bf(acc[rr] / l_s[r]);
  }
}

// ------------------------------------------------------------------
extern "C" void kernel_launch(void* const* d_in, const int* in_sizes, int n_in, void* d_out,
                              int out_size, void* d_ws, size_t ws_size, hipStream_t stream) {
  const float* local_in = (const float*)d_in[0];
  const float* centers = (const float*)d_in[1];
  const float* scales = (const float*)d_in[2];
  const float* scene_tok = (const float*)d_in[3];
  const float* periods = (const float*)d_in[4];
  const float* read_gate = (const float*)d_in[5];
  const float* write_gate = (const float*)d_in[6];
  const float* ln1w = (const float*)d_in[7];
  const float* ln1b = (const float*)d_in[8];
  const float* ln2w = (const float*)d_in[9];
  const float* ln2b = (const float*)d_in[10];
  const float* Wqkv = (const float*)d_in[11];
  const float* bqkv = (const float*)d_in[12];
  const float* Wp = (const float*)d_in[13];
  const float* bp = (const float*)d_in[14];
  const float* W1 = (const float*)d_in[15];
  const float* b1 = (const float*)d_in[16];
  const float* W2 = (const float*)d_in[17];
  const float* b2 = (const float*)d_in[18];
  const float* rqW = (const float*)d_in[19];
  const float* rqb = (const float*)d_in[20];
  const float* rkW = (const float*)d_in[21];
  const float* rkb = (const float*)d_in[22];
  const float* rvW = (const float*)d_in[23];
  const float* rvb = (const float*)d_in[24];
  const float* roW = (const float*)d_in[25];
  const float* rob = (const float*)d_in[26];
  const float* wqW = (const float*)d_in[27];
  const float* wqb = (const float*)d_in[28];
  const float* wkW = (const float*)d_in[29];
  const float* wkb = (const float*)d_in[30];
  const float* wvW = (const float*)d_in[31];
  const float* wvb = (const float*)d_in[32];
  const float* woW = (const float*)d_in[33];
  const float* wob = (const float*)d_in[34];

  float* out = (float*)d_out;
  float* local = out;                              // (3136, 768) fp32
  float* scene = out + (size_t)ML * DM;            // (16384, 768) fp32

  // workspace layout (bf16 = unsigned short)
  constexpr size_t E_WSLOT = 11796480;             // per-layer weights bf16 [N][K]
  constexpr size_t E_LBF = (size_t)ML_PAD * DM;    // 2457600
  constexpr size_t E_BUF = (size_t)MS * DM;        // 12582912
  unsigned short* wslot = (unsigned short*)d_ws;
  unsigned short* local_bf = wslot + E_WSLOT;
  unsigned short* scene_bf = local_bf + E_LBF;
  unsigned short* bufQ = scene_bf + E_BUF;
  unsigned short* bufK = bufQ + E_BUF;
  unsigned short* bufV = bufK + E_BUF;
  unsigned short* bufO = bufV + E_BUF;
  unsigned short* bufH = bufO + E_BUF;
  float* lcos = (float*)(bufH + E_LBF);
  float* lsin = lcos + BATCH * NLOC * 32;
  float* scos = lsin + BATCH * NLOC * 32;
  float* ssin = scos + NSC * 32;

  const int totOut = (ML + MS) * DM;
  init_out_k<<<(totOut + 255) / 256, 256, 0, stream>>>(local_in, scene_tok, out, local_bf,
                                                       scene_bf);
  rope_local_k<<<(BATCH * NLOC * 32 + 255) / 256, 256, 0, stream>>>(centers, scales, periods,
                                                                    lcos, lsin);
  rope_scene_k<<<(NSC * 32 + 255) / 256, 256, 0, stream>>>(periods, scos, ssin);

  const size_t DD = (size_t)DM * DM;
  const int LBS = NLOC * 32;
  const dim3 gS(6, MS / 128);    // scene-M 768-N
  const dim3 gL(6, ML_PAD / 128);  // local-M 768-N
  for (int i = 0; i < NLAYER; ++i) {
    SrcPtrs sp;
    sp.p[0] = Wqkv + (size_t)DM * 3 * DM * i;
    sp.p[1] = Wp + DD * i;
    sp.p[2] = W1 + (size_t)DM * 4 * DM * i;
    sp.p[3] = W2 + (size_t)4 * DM * DM * i;
    sp.p[4] = rqW + DD * i;
    sp.p[5] = rkW + DD * i;
    sp.p[6] = rvW + DD * i;
    sp.p[7] = roW + DD * i;
    sp.p[8] = wqW + DD * i;
    sp.p[9] = wkW + DD * i;
    sp.p[10] = wvW + DD * i;
    sp.p[11] = woW + DD * i;
    wconv_k<<<11520, 256, 0, stream>>>(sp, wslot);

    // ---- read cross-attn: local(49q) <- scene(256kv)
    gemm_mfma<0><<<gL, 256, 0, stream>>>(local_bf, wslot + W_RQ, rqb + DM * i, bufQ, nullptr,
                                         nullptr, ML, DM, DM);
    gemm_mfma<0><<<gS, 256, 0, stream>>>(scene_bf, wslot + W_RK, rkb + DM * i, bufK, nullptr,
                                         nullptr, MS, DM, DM);
    gemm_mfma<0><<<gS, 256, 0, stream>>>(scene_bf, wslot + W_RV, rvb + DM * i, bufV, nullptr,
                                         nullptr, MS, DM, DM);
    attn_k<<<dim3(BATCH * NHD * 2), 256, 0, stream>>>(bufQ, DM, bufK, DM, bufV, DM, bufO, lcos,
                                                      lsin, LBS, scos, ssin, 0, NLOC, NSC);
    gemm_mfma<2><<<gL, 256, 0, stream>>>(bufO, wslot + W_RO, rob + DM * i, local_bf, local,
                                         read_gate + DM * i, ML, DM, DM);
    // ---- backend block on local
    ln_k<<<ML / 4, 256, 0, stream>>>(local, ln1w + DM * i, ln1b + DM * i, bufH, ML);
    gemm_mfma<0><<<dim3(18, ML_PAD / 128), 256, 0, stream>>>(bufH, wslot + W_QKV,
                                                             bqkv + 3 * DM * i, bufQ, nullptr,
                                                             nullptr, ML, 3 * DM, DM);
    attn_k<<<dim3(BATCH * NHD * 2), 256, 0, stream>>>(bufQ, 3 * DM, bufQ + DM, 3 * DM,
                                                      bufQ + 2 * DM, 3 * DM, bufO, lcos, lsin,
                                                      LBS, lcos, lsin, LBS, NLOC, NLOC);
    gemm_mfma<2><<<gL, 256, 0, stream>>>(bufO, wslot + W_P, bp + DM * i, local_bf, local, nullptr,
                                         ML, DM, DM);
    ln_k<<<ML / 4, 256, 0, stream>>>(local, ln2w + DM * i, ln2b + DM * i, bufH, ML);
    gemm_mfma<1><<<dim3(24, ML_PAD / 128), 256, 0, stream>>>(bufH, wslot + W_1, b1 + 4 * DM * i,
                                                             bufO, nullptr, nullptr, ML, 4 * DM,
                                                             DM);
    gemm_mfma<2><<<gL, 256, 0, stream>>>(bufO, wslot + W_2, b2 + DM * i, local_bf, local, nullptr,
                                         ML, DM, 4 * DM);
    // ---- write cross-attn: scene(256q) <- local(49kv)
    gemm_mfma<0><<<gS, 256, 0, stream>>>(scene_bf, wslot + W_WQ, wqb + DM * i, bufQ, nullptr,
                                         nullptr, MS, DM, DM);
    gemm_mfma<0><<<gL, 256, 0, stream>>>(local_bf, wslot + W_WK, wkb + DM * i, bufK, nullptr,
                                         nullptr, ML, DM, DM);
    gemm_mfma<0><<<gL, 256, 0, stream>>>(local_bf, wslot + W_WV, wvb + DM * i, bufV, nullptr,
                                         nullptr, ML, DM, DM);
    attn_k<<<dim3(BATCH * NHD * 8), 256, 0, stream>>>(bufQ, DM, bufK, DM, bufV, DM, bufO, scos,
                                                      ssin, 0, lcos, lsin, LBS, NSC, NLOC);
    gemm_mfma<2><<<gS, 256, 0, stream>>>(bufO, wslot + W_WO, wob + DM * i, scene_bf, scene,
                                         write_gate + DM * i, MS, DM, DM);
  }
}

// Round 2
// 5489.103 us; speedup vs baseline: 1.4252x; 1.3596x over previous
//
#include <hip/hip_runtime.h>
#include <hip/hip_bf16.h>
#include <math.h>

#define BATCH 64
#define DM 768
#define NHD 12
#define NLAYER 8
#define NLOC 49
#define NSC 256
#define ATT_SCALE 0.125f
#define ML (BATCH * NLOC)      // 3136
#define ML_PAD 3200            // 25 * 128
#define MS (BATCH * NSC)       // 16384

typedef short bf16x8 __attribute__((ext_vector_type(8)));
typedef float f32x4 __attribute__((ext_vector_type(4)));

__device__ __forceinline__ float bf2f(unsigned short r) {
  return __uint_as_float(((unsigned)r) << 16);
}
__device__ __forceinline__ unsigned short f2bf(float x) {
  __hip_bfloat16 h = __float2bfloat16(x);
  unsigned short r;
  __builtin_memcpy(&r, &h, 2);
  return r;
}

// ------------------------------------------------------------------
// rope tables (fp32): lcos/lsin [3136][32], scos/ssin [256][32]
// ------------------------------------------------------------------
__global__ void rope_local_k(const float* __restrict__ centers, const float* __restrict__ scales,
                             const float* __restrict__ periods, float* __restrict__ lcos,
                             float* __restrict__ lsin) {
  int t = blockIdx.x * blockDim.x + threadIdx.x;
  const int total = BATCH * NLOC * 32;
  if (t >= total) return;
  int d = t & 31;
  int r = (t >> 5) % NLOC;
  int b = t / (NLOC * 32);
  int pi = d & 15;
  float gx = ((r % 7) + 0.5f) / 7.0f - 0.5f;
  float gy = ((r / 7) + 0.5f) / 7.0f - 0.5f;
  float coord = (d < 16) ? (centers[b * 2 + 0] + scales[b * 2 + 0] * gx)
                         : (centers[b * 2 + 1] + scales[b * 2 + 1] * gy);
  float ang = 6.283185307179586f * coord / periods[pi];
  lcos[t] = cosf(ang);
  lsin[t] = sinf(ang);
}

__global__ void rope_scene_k(const float* __restrict__ periods, float* __restrict__ scos,
                             float* __restrict__ ssin) {
  int t = blockIdx.x * blockDim.x + threadIdx.x;
  const int total = NSC * 32;
  if (t >= total) return;
  int d = t & 31;
  int r = t >> 5;
  int pi = d & 15;
  float coord = (d < 16) ? ((r % 16) + 0.5f) / 16.0f : ((r / 16) + 0.5f) / 16.0f;
  float ang = 6.283185307179586f * coord / periods[pi];
  scos[t] = cosf(ang);
  ssin[t] = sinf(ang);
}

// ------------------------------------------------------------------
// init: streams (fp32 in d_out) + bf16 mirrors
// ------------------------------------------------------------------
__global__ void init_out_k(const float* __restrict__ local_in, const float* __restrict__ scene_tok,
                           float* __restrict__ out, unsigned short* __restrict__ lbf,
                           unsigned short* __restrict__ sbf) {
  int t = blockIdx.x * blockDim.x + threadIdx.x;
  const int NL = ML * DM;
  const int NS = MS * DM;
  if (t < NL) {
    float v = local_in[t];
    out[t] = v;
    lbf[t] = f2bf(v);
  } else if (t < NL + NS) {
    float v = scene_tok[(t - NL) % (NSC * DM)];
    out[t] = v;
    sbf[t - NL] = f2bf(v);
  }
}

// zero the pad rows [ML, 3200) so attention tail tiles read exact zeros
__global__ void pad_zero_k(unsigned short* __restrict__ bq, unsigned short* __restrict__ bk,
                           unsigned short* __restrict__ bv) {
  int t = blockIdx.x * blockDim.x + threadIdx.x;
  if (t < 64 * 2304) bq[(size_t)ML * 2304 + t] = 0;
  if (t < 64 * 768) {
    bk[(size_t)ML * 768 + t] = 0;
    bv[(size_t)ML * 768 + t] = 0;
  }
}

// ------------------------------------------------------------------
// per-layer weight convert + transpose: fp32 [K,N] -> bf16 [N,K]
// ------------------------------------------------------------------
struct SrcPtrs {
  const float* p[12];
};

__constant__ const int wc_K[12] = {768, 768, 768, 3072, 768, 768, 768, 768, 768, 768, 768, 768};
__constant__ const int wc_N[12] = {2304, 768, 3072, 768, 768, 768, 768, 768, 768, 768, 768, 768};
__constant__ const int wc_blk[13] = {0,    1728, 2304, 4608, 6912,  7488,  8064,
                                     8640, 9216, 9792, 10368, 10944, 11520};
__constant__ const size_t wc_off[12] = {0,       1769472, 2359296, 4718592,
                                        7077888, 7667712, 8257536, 8847360,
                                        9437184, 10027008, 10616832, 11206656};
#define W_QKV 0
#define W_P 1769472
#define W_1 2359296
#define W_2 4718592
#define W_RQ 7077888
#define W_RK 7667712
#define W_RV 8257536
#define W_RO 8847360
#define W_WQ 9437184
#define W_WK 10027008
#define W_WV 10616832
#define W_WO 11206656

__global__ __launch_bounds__(256) void wconv_k(SrcPtrs sp, unsigned short* __restrict__ dst) {
  int b = blockIdx.x;
  int mi = 0;
  while (b >= wc_blk[mi + 1]) ++mi;
  int lb = b - wc_blk[mi];
  int K = wc_K[mi], N = wc_N[mi];
  int ncol = N >> 5;
  int kt = lb / ncol, nt = lb - kt * ncol;
  const float* src = sp.p[mi];
  __shared__ unsigned short tile[32][33];
  int r = threadIdx.x >> 3, c4 = (threadIdx.x & 7) << 2;
  float4 v = *(const float4*)(src + (size_t)(kt * 32 + r) * N + nt * 32 + c4);
  tile[r][c4 + 0] = f2bf(v.x);
  tile[r][c4 + 1] = f2bf(v.y);
  tile[r][c4 + 2] = f2bf(v.z);
  tile[r][c4 + 3] = f2bf(v.w);
  __syncthreads();
  unsigned short o[4];
  o[0] = tile[c4 + 0][r];
  o[1] = tile[c4 + 1][r];
  o[2] = tile[c4 + 2][r];
  o[3] = tile[c4 + 3][r];
  unsigned short* dp = dst + wc_off[mi] + (size_t)(nt * 32 + r) * K + kt * 32 + c4;
  *(ushort4*)dp = *(const ushort4*)o;
}

// ------------------------------------------------------------------
// bf16 MFMA GEMM: C[M,N] = A[M,K] @ Bt[N,K]^T + bias
// MODE 0: store bf16 Cb. MODE 1: exact GELU -> Cb.
// MODE 2: Cf += gate*(acc+bias) (fp32 stream) + bf16 mirror Cb.
// RMODE 0: none. RMODE 1: rope w/ per-row table [row*32+dd] (local).
// RMODE 2: rope w/ broadcast table [(row&255)*32+dd] (scene).
// Rope pairs cols (j*16+fm, j*16+fm+32) -> both held by same lane (j, j+2).
// Cols >= ropemax (v-part of qkv) skip rope. RMODE>0 implies MODE 0.
// ------------------------------------------------------------------
template <int MODE, int RMODE>
__global__ __launch_bounds__(256) void gemm_mfma(const unsigned short* __restrict__ A,
                                                 const unsigned short* __restrict__ Bt,
                                                 const float* __restrict__ bias,
                                                 unsigned short* __restrict__ Cb,
                                                 float* __restrict__ Cf,
                                                 const float* __restrict__ gate,
                                                 const float* __restrict__ rc,
                                                 const float* __restrict__ rsn, int ropemax,
                                                 int M, int N, int K) {
  __shared__ unsigned short As[128 * 64];
  __shared__ unsigned short Bs[128 * 64];
  const int tid = threadIdx.x;
  const int w = tid >> 6;
  const int lane = tid & 63;
  const int wm = w & 1, wn = w >> 1;
  const int bm = blockIdx.y << 7;
  const int bn = blockIdx.x << 7;
  const int lrow = lane >> 3;
  const int lchunk = lane & 7;
  const int schunk = lchunk ^ lrow;
  const int fm = lane & 15;
  const int quad = lane >> 4;

  f32x4 acc[4][4];
#pragma unroll
  for (int i = 0; i < 4; ++i)
#pragma unroll
    for (int j = 0; j < 4; ++j) acc[i][j] = (f32x4){0.f, 0.f, 0.f, 0.f};

  const size_t a_base = (size_t)(bm + w * 32 + lrow) * K + schunk * 8;
  const size_t b_base = (size_t)(bn + w * 32 + lrow) * K + schunk * 8;

  for (int k0 = 0; k0 < K; k0 += 64) {
    __syncthreads();
#pragma unroll
    for (int q = 0; q < 4; ++q) {
      const unsigned short* ga = A + a_base + (size_t)(q * 8) * K + k0;
      const unsigned short* gb = Bt + b_base + (size_t)(q * 8) * K + k0;
      __builtin_amdgcn_global_load_lds((const __attribute__((address_space(1))) void*)ga,
                                       (__attribute__((address_space(3))) void*)(As + (w * 32 + q * 8) * 64),
                                       16, 0, 0);
      __builtin_amdgcn_global_load_lds((const __attribute__((address_space(1))) void*)gb,
                                       (__attribute__((address_space(3))) void*)(Bs + (w * 32 + q * 8) * 64),
                                       16, 0, 0);
    }
    __syncthreads();
#pragma unroll
    for (int kc = 0; kc < 2; ++kc) {
      bf16x8 af[4], bfr[4];
#pragma unroll
      for (int i = 0; i < 4; ++i) {
        int ra = wm * 64 + i * 16 + fm;
        af[i] = *(const bf16x8*)(As + ra * 64 + (((kc * 4 + quad) ^ (ra & 7)) << 3));
      }
#pragma unroll
      for (int j = 0; j < 4; ++j) {
        int rb = wn * 64 + j * 16 + fm;
        bfr[j] = *(const bf16x8*)(Bs + rb * 64 + (((kc * 4 + quad) ^ (rb & 7)) << 3));
      }
#pragma unroll
      for (int i = 0; i < 4; ++i)
#pragma unroll
        for (int j = 0; j < 4; ++j)
          acc[i][j] = __builtin_amdgcn_mfma_f32_16x16x32_bf16(af[i], bfr[j], acc[i][j], 0, 0, 0);
    }
  }

  if constexpr (RMODE > 0) {
    // rope epilogue (MODE 0 semantics): pair (jp, jp+2) = dims (dd, dd+32)
#pragma unroll
    for (int jp = 0; jp < 2; ++jp) {
      const int colA = bn + wn * 64 + jp * 16 + fm;
      const int colB = colA + 32;
      const float bA = bias[colA];
      const float bB = bias[colB];
      const bool doRope = (colA < ropemax);
      const int ddv = (jp << 4) + fm;
#pragma unroll
      for (int i = 0; i < 4; ++i) {
#pragma unroll
        for (int reg = 0; reg < 4; ++reg) {
          const int row = bm + wm * 64 + i * 16 + quad * 4 + reg;
          if (row < M) {
            float x1 = acc[i][jp][reg] + bA;
            float x2 = acc[i][jp + 2][reg] + bB;
            if (doRope) {
              const int ti = (RMODE == 1) ? row : (row & 255);
              const float c = rc[ti * 32 + ddv];
              const float s = rsn[ti * 32 + ddv];
              const float y1 = x1 * c - x2 * s;
              x2 = x1 * s + x2 * c;
              x1 = y1;
            }
            const size_t base = (size_t)row * N;
            Cb[base + colA] = f2bf(x1);
            Cb[base + colB] = f2bf(x2);
          }
        }
      }
    }
  } else {
#pragma unroll
    for (int j = 0; j < 4; ++j) {
      const int col = bn + wn * 64 + j * 16 + fm;
      const float bj = bias[col];
      float gj = 1.0f;
      if (MODE == 2) gj = gate ? gate[col] : 1.0f;
#pragma unroll
      for (int i = 0; i < 4; ++i) {
#pragma unroll
        for (int reg = 0; reg < 4; ++reg) {
          const int row = bm + wm * 64 + i * 16 + quad * 4 + reg;
          if (row < M) {
            float v = acc[i][j][reg] + bj;
            if (MODE == 1) v = 0.5f * v * (1.0f + erff(v * 0.7071067811865475f));
            const size_t idx = (size_t)row * N + col;
            if (MODE == 2) {
              float o = Cf[idx] + gj * v;
              Cf[idx] = o;
              Cb[idx] = f2bf(o);
            } else {
              Cb[idx] = f2bf(v);
            }
          }
        }
      }
    }
  }
}

// ------------------------------------------------------------------
// LayerNorm over D=768; fp32 in, bf16 out; one wave per row
// ------------------------------------------------------------------
__global__ __launch_bounds__(256) void ln_k(const float* __restrict__ X,
                                            const float* __restrict__ w,
                                            const float* __restrict__ bb,
                                            unsigned short* __restrict__ Y, int rows) {
  const int wid = threadIdx.x >> 6, lane = threadIdx.x & 63;
  const int row = blockIdx.x * 4 + wid;
  if (row >= rows) return;
  const float* x = X + (size_t)row * DM;
  float v[12];
  float s = 0.f;
#pragma unroll
  for (int j = 0; j < 12; ++j) {
    v[j] = x[lane + 64 * j];
    s += v[j];
  }
#pragma unroll
  for (int o = 32; o; o >>= 1) s += __shfl_xor(s, o, 64);
  float mean = s * (1.0f / 768.0f);
  float q = 0.f;
#pragma unroll
  for (int j = 0; j < 12; ++j) {
    float d0 = v[j] - mean;
    q += d0 * d0;
  }
#pragma unroll
  for (int o = 32; o; o >>= 1) q += __shfl_xor(q, o, 64);
  float inv = rsqrtf(q * (1.0f / 768.0f) + 1e-6f);
#pragma unroll
  for (int j = 0; j < 12; ++j) {
    int d0 = lane + 64 * j;
    Y[(size_t)row * DM + d0] = f2bf((v[j] - mean) * inv * w[d0] + bb[d0]);
  }
}

// ------------------------------------------------------------------
// Fused flash attention on PRE-ROPED bf16 Q/K.
// 4 waves, 32 q-rows/block, 64-key tiles. Q/K/V staged via
// global_load_lds 16B (K/Q chunk-XOR swizzled, V linear). MFMA QK^T,
// all-rows-parallel online softmax, VALU PV from LDS V.
// Pad rows (>= Nq/Nk real rows) are zeros in global (pad_zero_k).
// ------------------------------------------------------------------
__global__ __launch_bounds__(256) void attn_k(const unsigned short* __restrict__ Q, int qs,
                                              const unsigned short* __restrict__ K, int ks,
                                              const unsigned short* __restrict__ V, int vs,
                                              unsigned short* __restrict__ O, int Nq, int Nk) {
  __shared__ unsigned short q_s[32 * 64];
  __shared__ unsigned short k_s[64 * 64];
  __shared__ unsigned short v_s[64 * 64];
  __shared__ __align__(16) float sc[32][68];
  __shared__ float m_s[32], l_s[32], rs_s[32];

  const int tid = threadIdx.x;
  const int nQT = (Nq + 31) >> 5;
  const int qt = blockIdx.x % nQT;
  const int h = (blockIdx.x / nQT) % NHD;
  const int b = blockIdx.x / (nQT * NHD);
  const int n0 = qt << 5;
  const int nrows = (Nq - n0 < 32) ? (Nq - n0) : 32;

  const int w = tid >> 6;
  const int lane = tid & 63;
  const int fm = lane & 15;
  const int quad = lane >> 4;
  const int lrow = lane >> 3;
  const int lchunk = lane & 7;
  const int schunk = lchunk ^ lrow;

  if (tid < 32) {
    m_s[tid] = -1e30f;
    l_s[tid] = 0.f;
  }

  // stage Q (32 rows): one 16B gl_lds per wave, rows w*8 + lrow
  {
    const unsigned short* gq =
        Q + ((size_t)b * Nq + n0 + w * 8 + lrow) * qs + h * 64 + schunk * 8;
    __builtin_amdgcn_global_load_lds((const __attribute__((address_space(1))) void*)gq,
                                     (__attribute__((address_space(3))) void*)(q_s + w * 8 * 64),
                                     16, 0, 0);
  }

  float acc[8] = {0.f, 0.f, 0.f, 0.f, 0.f, 0.f, 0.f, 0.f};

  for (int m0 = 0; m0 < Nk; m0 += 64) {
    const int mc = (Nk - m0 < 64) ? (Nk - m0) : 64;
    __syncthreads();  // prev PV done with v_s/sc
    // stage K (swizzled) + V (linear): rows w*16 + g*8 + lrow
#pragma unroll
    for (int g = 0; g < 2; ++g) {
      const int rg = w * 16 + g * 8;
      const size_t grow = (size_t)b * Nk + m0 + rg + lrow;
      const unsigned short* gk = K + grow * ks + h * 64 + schunk * 8;
      const unsigned short* gv = V + grow * vs + h * 64 + lchunk * 8;
      __builtin_amdgcn_global_load_lds((const __attribute__((address_space(1))) void*)gk,
                                       (__attribute__((address_space(3))) void*)(k_s + rg * 64),
                                       16, 0, 0);
      __builtin_amdgcn_global_load_lds((const __attribute__((address_space(1))) void*)gv,
                                       (__attribute__((address_space(3))) void*)(v_s + rg * 64),
                                       16, 0, 0);
    }
    __syncthreads();  // loads drained (compiler vmcnt(0) before barrier) + visible

    // QK^T MFMA: wave -> row-tile (w&1), col-tiles (w>>1)*2 + {0,1}
    {
      const int rt = w & 1;
      const int arow = (rt << 4) + fm;
      const bf16x8 a0 = *(const bf16x8*)(q_s + (arow << 6) + ((quad ^ (arow & 7)) << 3));
      const bf16x8 a1 = *(const bf16x8*)(q_s + (arow << 6) + (((4 + quad) ^ (arow & 7)) << 3));
      const int ct0 = (w >> 1) << 1;
#pragma unroll
      for (int j = 0; j < 2; ++j) {
        const int brow = ((ct0 + j) << 4) + fm;
        const bf16x8 b0 = *(const bf16x8*)(k_s + (brow << 6) + ((quad ^ (brow & 7)) << 3));
        const bf16x8 b1 = *(const bf16x8*)(k_s + (brow << 6) + (((4 + quad) ^ (brow & 7)) << 3));
        f32x4 sv = (f32x4){0.f, 0.f, 0.f, 0.f};
        sv = __builtin_amdgcn_mfma_f32_16x16x32_bf16(a0, b0, sv, 0, 0, 0);
        sv = __builtin_amdgcn_mfma_f32_16x16x32_bf16(a1, b1, sv, 0, 0, 0);
        const int srow = (rt << 4) + (quad << 2);
        const int scol = ((ct0 + j) << 4) + fm;
#pragma unroll
        for (int reg = 0; reg < 4; ++reg) sc[srow + reg][scol] = sv[reg] * ATT_SCALE;
      }
    }
    __syncthreads();

    // online softmax, all 32 rows in parallel: row = w*8+lrow, 8 cols per lane
    {
      const int r = (w << 3) + lrow;
      const int c0 = lchunk << 3;
      float4 pa = *(const float4*)&sc[r][c0];
      float4 pb = *(const float4*)&sc[r][c0 + 4];
      float vv[8] = {pa.x, pa.y, pa.z, pa.w, pb.x, pb.y, pb.z, pb.w};
      float mx = -1e30f;
#pragma unroll
      for (int e = 0; e < 8; ++e) {
        if (c0 + e >= mc) vv[e] = -1e30f;
        mx = fmaxf(mx, vv[e]);
      }
      mx = fmaxf(mx, __shfl_xor(mx, 1, 64));
      mx = fmaxf(mx, __shfl_xor(mx, 2, 64));
      mx = fmaxf(mx, __shfl_xor(mx, 4, 64));
      const float mo = m_s[r];
      const float mn = fmaxf(mo, mx);
      float sum = 0.f;
#pragma unroll
      for (int e = 0; e < 8; ++e) {
        const float ev = (c0 + e < mc) ? __expf(vv[e] - mn) : 0.f;
        vv[e] = ev;
        sum += ev;
      }
      *(float4*)&sc[r][c0] = (float4){vv[0], vv[1], vv[2], vv[3]};
      *(float4*)&sc[r][c0 + 4] = (float4){vv[4], vv[5], vv[6], vv[7]};
      sum += __shfl_xor(sum, 1, 64);
      sum += __shfl_xor(sum, 2, 64);
      sum += __shfl_xor(sum, 4, 64);
      if (lchunk == 0) {
        const float sca = __expf(mo - mn);
        rs_s[r] = sca;
        l_s[r] = l_s[r] * sca + sum;
        m_s[r] = mn;
      }
    }
    __syncthreads();

    // PV from LDS (full 64 cols; pad cols have p=0, pad V rows are 0)
#pragma unroll
    for (int rr = 0; rr < 8; ++rr) acc[rr] *= rs_s[w + (rr << 2)];
#pragma unroll 4
    for (int m = 0; m < 64; m += 4) {
      float4 p[8];
#pragma unroll
      for (int rr = 0; rr < 8; ++rr) p[rr] = *(const float4*)&sc[w + (rr << 2)][m];
      const float v0 = bf2f(v_s[(m + 0) * 64 + lane]);
      const float v1 = bf2f(v_s[(m + 1) * 64 + lane]);
      const float v2 = bf2f(v_s[(m + 2) * 64 + lane]);
      const float v3 = bf2f(v_s[(m + 3) * 64 + lane]);
#pragma unroll
      for (int rr = 0; rr < 8; ++rr) {
        acc[rr] = fmaf(p[rr].x, v0, acc[rr]);
        acc[rr] = fmaf(p[rr].y, v1, acc[rr]);
        acc[rr] = fmaf(p[rr].z, v2, acc[rr]);
        acc[rr] = fmaf(p[rr].w, v3, acc[rr]);
      }
    }
  }

  // epilogue: O = acc / l  (l_s synced at last softmax barrier)
#pragma unroll
  for (int rr = 0; rr < 8; ++rr) {
    const int r = w + (rr << 2);
    if (r < nrows)
      O[((size_t)b * Nq + n0 + r) * DM + h * 64 + lane] = f2bf(acc[rr] / l_s[r]);
  }
}

// ------------------------------------------------------------------
extern "C" void kernel_launch(void* const* d_in, const int* in_sizes, int n_in, void* d_out,
                              int out_size, void* d_ws, size_t ws_size, hipStream_t stream) {
  const float* local_in = (const float*)d_in[0];
  const float* centers = (const float*)d_in[1];
  const float* scales = (const float*)d_in[2];
  const float* scene_tok = (const float*)d_in[3];
  const float* periods = (const float*)d_in[4];
  const float* read_gate = (const float*)d_in[5];
  const float* write_gate = (const float*)d_in[6];
  const float* ln1w = (const float*)d_in[7];
  const float* ln1b = (const float*)d_in[8];
  const float* ln2w = (const float*)d_in[9];
  const float* ln2b = (const float*)d_in[10];
  const float* Wqkv = (const float*)d_in[11];
  const float* bqkv = (const float*)d_in[12];
  const float* Wp = (const float*)d_in[13];
  const float* bp = (const float*)d_in[14];
  const float* W1 = (const float*)d_in[15];
  const float* b1 = (const float*)d_in[16];
  const float* W2 = (const float*)d_in[17];
  const float* b2 = (const float*)d_in[18];
  const float* rqW = (const float*)d_in[19];
  const float* rqb = (const float*)d_in[20];
  const float* rkW = (const float*)d_in[21];
  const float* rkb = (const float*)d_in[22];
  const float* rvW = (const float*)d_in[23];
  const float* rvb = (const float*)d_in[24];
  const float* roW = (const float*)d_in[25];
  const float* rob = (const float*)d_in[26];
  const float* wqW = (const float*)d_in[27];
  const float* wqb = (const float*)d_in[28];
  const float* wkW = (const float*)d_in[29];
  const float* wkb = (const float*)d_in[30];
  const float* wvW = (const float*)d_in[31];
  const float* wvb = (const float*)d_in[32];
  const float* woW = (const float*)d_in[33];
  const float* wob = (const float*)d_in[34];

  float* out = (float*)d_out;
  float* local = out;                              // (3136, 768) fp32
  float* scene = out + (size_t)ML * DM;            // (16384, 768) fp32

  // workspace layout (bf16 = unsigned short)
  constexpr size_t E_WSLOT = 11796480;             // per-layer weights bf16 [N][K]
  constexpr size_t E_LBF = (size_t)ML_PAD * DM;    // 2457600
  constexpr size_t E_BUF = (size_t)MS * DM;        // 12582912
  unsigned short* wslot = (unsigned short*)d_ws;
  unsigned short* local_bf = wslot + E_WSLOT;
  unsigned short* scene_bf = local_bf + E_LBF;
  unsigned short* bufQ = scene_bf + E_BUF;
  unsigned short* bufK = bufQ + E_BUF;
  unsigned short* bufV = bufK + E_BUF;
  unsigned short* bufO = bufV + E_BUF;
  unsigned short* bufH = bufO + E_BUF;
  float* lcos = (float*)(bufH + E_LBF);
  float* lsin = lcos + BATCH * NLOC * 32;
  float* scos = lsin + BATCH * NLOC * 32;
  float* ssin = scos + NSC * 32;

  const int totOut = (ML + MS) * DM;
  init_out_k<<<(totOut + 255) / 256, 256, 0, stream>>>(local_in, scene_tok, out, local_bf,
                                                       scene_bf);
  pad_zero_k<<<(64 * 2304 + 255) / 256, 256, 0, stream>>>(bufQ, bufK, bufV);
  rope_local_k<<<(BATCH * NLOC * 32 + 255) / 256, 256, 0, stream>>>(centers, scales, periods,
                                                                    lcos, lsin);
  rope_scene_k<<<(NSC * 32 + 255) / 256, 256, 0, stream>>>(periods, scos, ssin);

  const size_t DD = (size_t)DM * DM;
  const dim3 gS(6, MS / 128);      // scene-M 768-N
  const dim3 gL(6, ML_PAD / 128);  // local-M 768-N
  for (int i = 0; i < NLAYER; ++i) {
    SrcPtrs sp;
    sp.p[0] = Wqkv + (size_t)DM * 3 * DM * i;
    sp.p[1] = Wp + DD * i;
    sp.p[2] = W1 + (size_t)DM * 4 * DM * i;
    sp.p[3] = W2 + (size_t)4 * DM * DM * i;
    sp.p[4] = rqW + DD * i;
    sp.p[5] = rkW + DD * i;
    sp.p[6] = rvW + DD * i;
    sp.p[7] = roW + DD * i;
    sp.p[8] = wqW + DD * i;
    sp.p[9] = wkW + DD * i;
    sp.p[10] = wvW + DD * i;
    sp.p[11] = woW + DD * i;
    wconv_k<<<11520, 256, 0, stream>>>(sp, wslot);

    // ---- read cross-attn: local(49q) <- scene(256kv)
    gemm_mfma<0, 1><<<gL, 256, 0, stream>>>(local_bf, wslot + W_RQ, rqb + DM * i, bufQ, nullptr,
                                            nullptr, lcos, lsin, DM, ML, DM, DM);
    gemm_mfma<0, 2><<<gS, 256, 0, stream>>>(scene_bf, wslot + W_RK, rkb + DM * i, bufK, nullptr,
                                            nullptr, scos, ssin, DM, MS, DM, DM);
    gemm_mfma<0, 0><<<gS, 256, 0, stream>>>(scene_bf, wslot + W_RV, rvb + DM * i, bufV, nullptr,
                                            nullptr, nullptr, nullptr, 0, MS, DM, DM);
    attn_k<<<dim3(BATCH * NHD * 2), 256, 0, stream>>>(bufQ, DM, bufK, DM, bufV, DM, bufO, NLOC,
                                                      NSC);
    gemm_mfma<2, 0><<<gL, 256, 0, stream>>>(bufO, wslot + W_RO, rob + DM * i, local_bf, local,
                                            read_gate + DM * i, nullptr, nullptr, 0, ML, DM, DM);
    // ---- backend block on local
    ln_k<<<ML / 4, 256, 0, stream>>>(local, ln1w + DM * i, ln1b + DM * i, bufH, ML);
    gemm_mfma<0, 1><<<dim3(18, ML_PAD / 128), 256, 0, stream>>>(bufH, wslot + W_QKV,
                                                                bqkv + 3 * DM * i, bufQ, nullptr,
                                                                nullptr, lcos, lsin, 2 * DM, ML,
                                                                3 * DM, DM);
    attn_k<<<dim3(BATCH * NHD * 2), 256, 0, stream>>>(bufQ, 3 * DM, bufQ + DM, 3 * DM,
                                                      bufQ + 2 * DM, 3 * DM, bufO, NLOC, NLOC);
    gemm_mfma<2, 0><<<gL, 256, 0, stream>>>(bufO, wslot + W_P, bp + DM * i, local_bf, local,
                                            nullptr, nullptr, nullptr, 0, ML, DM, DM);
    ln_k<<<ML / 4, 256, 0, stream>>>(local, ln2w + DM * i, ln2b + DM * i, bufH, ML);
    gemm_mfma<1, 0><<<dim3(24, ML_PAD / 128), 256, 0, stream>>>(bufH, wslot + W_1,
                                                                b1 + 4 * DM * i, bufO, nullptr,
                                                                nullptr, nullptr, nullptr, 0, ML,
                                                                4 * DM, DM);
    gemm_mfma<2, 0><<<gL, 256, 0, stream>>>(bufO, wslot + W_2, b2 + DM * i, local_bf, local,
                                            nullptr, nullptr, nullptr, 0, ML, DM, 4 * DM);
    // ---- write cross-attn: scene(256q) <- local(49kv)
    gemm_mfma<0, 2><<<gS, 256, 0, stream>>>(scene_bf, wslot + W_WQ, wqb + DM * i, bufQ, nullptr,
                                            nullptr, scos, ssin, DM, MS, DM, DM);
    gemm_mfma<0, 1><<<gL, 256, 0, stream>>>(local_bf, wslot + W_WK, wkb + DM * i, bufK, nullptr,
                                            nullptr, lcos, lsin, DM, ML, DM, DM);
    gemm_mfma<0, 0><<<gL, 256, 0, stream>>>(local_bf, wslot + W_WV, wvb + DM * i, bufV, nullptr,
                                            nullptr, nullptr, nullptr, 0, ML, DM, DM);
    attn_k<<<dim3(BATCH * NHD * 8), 256, 0, stream>>>(bufQ, DM, bufK, DM, bufV, DM, bufO, NSC,
                                                      NLOC);
    gemm_mfma<2, 0><<<gS, 256, 0, stream>>>(bufO, wslot + W_WO, wob + DM * i, scene_bf, scene,
                                            write_gate + DM * i, nullptr, nullptr, 0, MS, DM, DM);
  }
}

// Round 3
// 5150.386 us; speedup vs baseline: 1.5190x; 1.0658x over previous
//
#include <hip/hip_runtime.h>
#include <hip/hip_bf16.h>
#include <math.h>

#define BATCH 64
#define DM 768
#define NHD 12
#define NLAYER 8
#define NLOC 49
#define NSC 256
#define ATT_SCALE 0.125f
#define ML (BATCH * NLOC)      // 3136
#define ML_PAD 3200            // 25 * 128
#define MS (BATCH * NSC)       // 16384

typedef short bf16x8 __attribute__((ext_vector_type(8)));
typedef float f32x4 __attribute__((ext_vector_type(4)));

__device__ __forceinline__ float bf2f(unsigned short r) {
  return __uint_as_float(((unsigned)r) << 16);
}
__device__ __forceinline__ unsigned short f2bf(float x) {
  __hip_bfloat16 h = __float2bfloat16(x);
  unsigned short r;
  __builtin_memcpy(&r, &h, 2);
  return r;
}

// ------------------------------------------------------------------
// rope tables (fp32): lcos/lsin [3136][32], scos/ssin [256][32]
// ------------------------------------------------------------------
__global__ void rope_local_k(const float* __restrict__ centers, const float* __restrict__ scales,
                             const float* __restrict__ periods, float* __restrict__ lcos,
                             float* __restrict__ lsin) {
  int t = blockIdx.x * blockDim.x + threadIdx.x;
  const int total = BATCH * NLOC * 32;
  if (t >= total) return;
  int d = t & 31;
  int r = (t >> 5) % NLOC;
  int b = t / (NLOC * 32);
  int pi = d & 15;
  float gx = ((r % 7) + 0.5f) / 7.0f - 0.5f;
  float gy = ((r / 7) + 0.5f) / 7.0f - 0.5f;
  float coord = (d < 16) ? (centers[b * 2 + 0] + scales[b * 2 + 0] * gx)
                         : (centers[b * 2 + 1] + scales[b * 2 + 1] * gy);
  float ang = 6.283185307179586f * coord / periods[pi];
  lcos[t] = cosf(ang);
  lsin[t] = sinf(ang);
}

__global__ void rope_scene_k(const float* __restrict__ periods, float* __restrict__ scos,
                             float* __restrict__ ssin) {
  int t = blockIdx.x * blockDim.x + threadIdx.x;
  const int total = NSC * 32;
  if (t >= total) return;
  int d = t & 31;
  int r = t >> 5;
  int pi = d & 15;
  float coord = (d < 16) ? ((r % 16) + 0.5f) / 16.0f : ((r / 16) + 0.5f) / 16.0f;
  float ang = 6.283185307179586f * coord / periods[pi];
  scos[t] = cosf(ang);
  ssin[t] = sinf(ang);
}

// ------------------------------------------------------------------
// init: streams (fp32 in d_out) + bf16 mirrors
// ------------------------------------------------------------------
__global__ void init_out_k(const float* __restrict__ local_in, const float* __restrict__ scene_tok,
                           float* __restrict__ out, unsigned short* __restrict__ lbf,
                           unsigned short* __restrict__ sbf) {
  int t = blockIdx.x * blockDim.x + threadIdx.x;
  const int NL = ML * DM;
  const int NS = MS * DM;
  if (t < NL) {
    float v = local_in[t];
    out[t] = v;
    lbf[t] = f2bf(v);
  } else if (t < NL + NS) {
    float v = scene_tok[(t - NL) % (NSC * DM)];
    out[t] = v;
    sbf[t - NL] = f2bf(v);
  }
}

// ------------------------------------------------------------------
// per-layer weight convert + transpose: fp32 [K,N] -> bf16 [N,K]
// ------------------------------------------------------------------
struct SrcPtrs {
  const float* p[12];
};

__constant__ const int wc_K[12] = {768, 768, 768, 3072, 768, 768, 768, 768, 768, 768, 768, 768};
__constant__ const int wc_N[12] = {2304, 768, 3072, 768, 768, 768, 768, 768, 768, 768, 768, 768};
__constant__ const int wc_blk[13] = {0,    1728, 2304, 4608, 6912,  7488,  8064,
                                     8640, 9216, 9792, 10368, 10944, 11520};
__constant__ const size_t wc_off[12] = {0,       1769472, 2359296, 4718592,
                                        7077888, 7667712, 8257536, 8847360,
                                        9437184, 10027008, 10616832, 11206656};
#define W_QKV 0
#define W_P 1769472
#define W_1 2359296
#define W_2 4718592
#define W_RQ 7077888
#define W_RK 7667712
#define W_RV 8257536
#define W_RO 8847360
#define W_WQ 9437184
#define W_WK 10027008
#define W_WV 10616832
#define W_WO 11206656

__global__ __launch_bounds__(256) void wconv_k(SrcPtrs sp, unsigned short* __restrict__ dst) {
  int b = blockIdx.x;
  int mi = 0;
  while (b >= wc_blk[mi + 1]) ++mi;
  int lb = b - wc_blk[mi];
  int K = wc_K[mi], N = wc_N[mi];
  int ncol = N >> 5;
  int kt = lb / ncol, nt = lb - kt * ncol;
  const float* src = sp.p[mi];
  __shared__ unsigned short tile[32][33];
  int r = threadIdx.x >> 3, c4 = (threadIdx.x & 7) << 2;
  float4 v = *(const float4*)(src + (size_t)(kt * 32 + r) * N + nt * 32 + c4);
  tile[r][c4 + 0] = f2bf(v.x);
  tile[r][c4 + 1] = f2bf(v.y);
  tile[r][c4 + 2] = f2bf(v.z);
  tile[r][c4 + 3] = f2bf(v.w);
  __syncthreads();
  unsigned short o[4];
  o[0] = tile[c4 + 0][r];
  o[1] = tile[c4 + 1][r];
  o[2] = tile[c4 + 2][r];
  o[3] = tile[c4 + 3][r];
  unsigned short* dp = dst + wc_off[mi] + (size_t)(nt * 32 + r) * K + kt * 32 + c4;
  *(ushort4*)dp = *(const ushort4*)o;
}

// ------------------------------------------------------------------
// bf16 MFMA GEMM: C[M,N] = A[M,K] @ Bt[N,K]^T + bias
// MODE 0: store bf16 Cb. MODE 1: exact GELU -> Cb.
// MODE 2: Cf += gate*(acc+bias) (fp32 stream) + bf16 mirror Cb.
// RMODE 0: none. RMODE 1: rope w/ per-row table [row*32+dd] (local).
// RMODE 2: rope w/ broadcast table [(row&255)*32+dd] (scene).
// Rope pairs cols (j*16+fm, j*16+fm+32), both held by same lane (j, j+2).
// Cols >= ropemax skip rope. bias2 (if set) serves cols >= 768 (fused KV).
// Rows [M, Mpad) are written as zeros (attention pad rows).
// XCD-chunked block swizzle: each XCD gets a contiguous x-major tile
// chunk so its A-panel (~3MB) stays in its private 4MB L2.
// ------------------------------------------------------------------
template <int MODE, int RMODE>
__global__ __launch_bounds__(256) void gemm_mfma(const unsigned short* __restrict__ A,
                                                 const unsigned short* __restrict__ Bt,
                                                 const float* __restrict__ bias,
                                                 const float* __restrict__ bias2,
                                                 unsigned short* __restrict__ Cb,
                                                 float* __restrict__ Cf,
                                                 const float* __restrict__ gate,
                                                 const float* __restrict__ rc,
                                                 const float* __restrict__ rsn, int ropemax,
                                                 int M, int Mpad, int N, int K) {
  __shared__ unsigned short As[128 * 64];
  __shared__ unsigned short Bs[128 * 64];
  const int tid = threadIdx.x;
  const int w = tid >> 6;
  const int lane = tid & 63;
  const int wm = w & 1, wn = w >> 1;

  // bijective XCD-chunked swizzle (8 XCDs, round-robin hw assignment)
  int bx, by;
  {
    const int gx = gridDim.x;
    const int nwg = gx * gridDim.y;
    const int lin = blockIdx.x + blockIdx.y * gx;
    const int q = nwg >> 3, r = nwg & 7;
    const int xcd = lin & 7, pos = lin >> 3;
    const int nl = xcd * q + (xcd < r ? xcd : r) + pos;
    bx = nl % gx;
    by = nl / gx;
  }
  const int bm = by << 7;
  const int bn = bx << 7;

  const int lrow = lane >> 3;
  const int lchunk = lane & 7;
  const int schunk = lchunk ^ lrow;
  const int fm = lane & 15;
  const int quad = lane >> 4;

  f32x4 acc[4][4];
#pragma unroll
  for (int i = 0; i < 4; ++i)
#pragma unroll
    for (int j = 0; j < 4; ++j) acc[i][j] = (f32x4){0.f, 0.f, 0.f, 0.f};

  const size_t a_base = (size_t)(bm + w * 32 + lrow) * K + schunk * 8;
  const size_t b_base = (size_t)(bn + w * 32 + lrow) * K + schunk * 8;

  for (int k0 = 0; k0 < K; k0 += 64) {
    __syncthreads();
#pragma unroll
    for (int q = 0; q < 4; ++q) {
      const unsigned short* ga = A + a_base + (size_t)(q * 8) * K + k0;
      const unsigned short* gb = Bt + b_base + (size_t)(q * 8) * K + k0;
      __builtin_amdgcn_global_load_lds((const __attribute__((address_space(1))) void*)ga,
                                       (__attribute__((address_space(3))) void*)(As + (w * 32 + q * 8) * 64),
                                       16, 0, 0);
      __builtin_amdgcn_global_load_lds((const __attribute__((address_space(1))) void*)gb,
                                       (__attribute__((address_space(3))) void*)(Bs + (w * 32 + q * 8) * 64),
                                       16, 0, 0);
    }
    __syncthreads();
#pragma unroll
    for (int kc = 0; kc < 2; ++kc) {
      bf16x8 af[4], bfr[4];
#pragma unroll
      for (int i = 0; i < 4; ++i) {
        int ra = wm * 64 + i * 16 + fm;
        af[i] = *(const bf16x8*)(As + ra * 64 + (((kc * 4 + quad) ^ (ra & 7)) << 3));
      }
#pragma unroll
      for (int j = 0; j < 4; ++j) {
        int rb = wn * 64 + j * 16 + fm;
        bfr[j] = *(const bf16x8*)(Bs + rb * 64 + (((kc * 4 + quad) ^ (rb & 7)) << 3));
      }
#pragma unroll
      for (int i = 0; i < 4; ++i)
#pragma unroll
        for (int j = 0; j < 4; ++j)
          acc[i][j] = __builtin_amdgcn_mfma_f32_16x16x32_bf16(af[i], bfr[j], acc[i][j], 0, 0, 0);
    }
  }

  if constexpr (RMODE > 0) {
    // rope epilogue: pair (jp, jp+2) = dims (dd, dd+32) of a 64-col head band
#pragma unroll
    for (int jp = 0; jp < 2; ++jp) {
      const int colA = bn + wn * 64 + jp * 16 + fm;
      const int colB = colA + 32;
      const float bA = (bias2 && colA >= 768) ? bias2[colA - 768] : bias[colA];
      const float bB = (bias2 && colA >= 768) ? bias2[colB - 768] : bias[colB];
      const bool doRope = (colA < ropemax);
      const int ddv = (jp << 4) + fm;
#pragma unroll
      for (int i = 0; i < 4; ++i) {
#pragma unroll
        for (int reg = 0; reg < 4; ++reg) {
          const int row = bm + wm * 64 + i * 16 + quad * 4 + reg;
          if (row < M) {
            float x1 = acc[i][jp][reg] + bA;
            float x2 = acc[i][jp + 2][reg] + bB;
            if (doRope) {
              const int ti = (RMODE == 1) ? row : (row & 255);
              const float c = rc[ti * 32 + ddv];
              const float s = rsn[ti * 32 + ddv];
              const float y1 = x1 * c - x2 * s;
              x2 = x1 * s + x2 * c;
              x1 = y1;
            }
            const size_t base = (size_t)row * N;
            Cb[base + colA] = f2bf(x1);
            Cb[base + colB] = f2bf(x2);
          } else if (row < Mpad) {
            const size_t base = (size_t)row * N;
            Cb[base + colA] = 0;
            Cb[base + colB] = 0;
          }
        }
      }
    }
  } else {
#pragma unroll
    for (int j = 0; j < 4; ++j) {
      const int col = bn + wn * 64 + j * 16 + fm;
      const float bj = bias[col];
      float gj = 1.0f;
      if (MODE == 2) gj = gate ? gate[col] : 1.0f;
#pragma unroll
      for (int i = 0; i < 4; ++i) {
#pragma unroll
        for (int reg = 0; reg < 4; ++reg) {
          const int row = bm + wm * 64 + i * 16 + quad * 4 + reg;
          if (row < M) {
            float v = acc[i][j][reg] + bj;
            if (MODE == 1) v = 0.5f * v * (1.0f + erff(v * 0.7071067811865475f));
            const size_t idx = (size_t)row * N + col;
            if (MODE == 2) {
              float o = Cf[idx] + gj * v;
              Cf[idx] = o;
              Cb[idx] = f2bf(o);
            } else {
              Cb[idx] = f2bf(v);
            }
          } else if (row < Mpad && MODE == 0) {
            Cb[(size_t)row * N + col] = 0;
          }
        }
      }
    }
  }
}

// ------------------------------------------------------------------
// LayerNorm over D=768; fp32 in, bf16 out; one wave per row
// ------------------------------------------------------------------
__global__ __launch_bounds__(256) void ln_k(const float* __restrict__ X,
                                            const float* __restrict__ w,
                                            const float* __restrict__ bb,
                                            unsigned short* __restrict__ Y, int rows) {
  const int wid = threadIdx.x >> 6, lane = threadIdx.x & 63;
  const int row = blockIdx.x * 4 + wid;
  if (row >= rows) return;
  const float* x = X + (size_t)row * DM;
  float v[12];
  float s = 0.f;
#pragma unroll
  for (int j = 0; j < 12; ++j) {
    v[j] = x[lane + 64 * j];
    s += v[j];
  }
#pragma unroll
  for (int o = 32; o; o >>= 1) s += __shfl_xor(s, o, 64);
  float mean = s * (1.0f / 768.0f);
  float q = 0.f;
#pragma unroll
  for (int j = 0; j < 12; ++j) {
    float d0 = v[j] - mean;
    q += d0 * d0;
  }
#pragma unroll
  for (int o = 32; o; o >>= 1) q += __shfl_xor(q, o, 64);
  float inv = rsqrtf(q * (1.0f / 768.0f) + 1e-6f);
#pragma unroll
  for (int j = 0; j < 12; ++j) {
    int d0 = lane + 64 * j;
    Y[(size_t)row * DM + d0] = f2bf((v[j] - mean) * inv * w[d0] + bb[d0]);
  }
}

// ------------------------------------------------------------------
// Fused flash attention on PRE-ROPED bf16 Q/K.
// 4 waves, 32 q-rows/block, 64-key tiles. Q/K/V staged via
// global_load_lds 16B (K/Q chunk-XOR swizzled, V linear). MFMA QK^T,
// all-rows-parallel online softmax, VALU PV from LDS V.
// Pad rows (>= Nq/Nk real rows) are zeros in global (gemm Mpad epilogue).
// ------------------------------------------------------------------
__global__ __launch_bounds__(256) void attn_k(const unsigned short* __restrict__ Q, int qs,
                                              const unsigned short* __restrict__ K, int ks,
                                              const unsigned short* __restrict__ V, int vs,
                                              unsigned short* __restrict__ O, int Nq, int Nk) {
  __shared__ unsigned short q_s[32 * 64];
  __shared__ unsigned short k_s[64 * 64];
  __shared__ unsigned short v_s[64 * 64];
  __shared__ __align__(16) float sc[32][68];
  __shared__ float m_s[32], l_s[32], rs_s[32];

  const int tid = threadIdx.x;
  const int nQT = (Nq + 31) >> 5;
  const int qt = blockIdx.x % nQT;
  const int h = (blockIdx.x / nQT) % NHD;
  const int b = blockIdx.x / (nQT * NHD);
  const int n0 = qt << 5;
  const int nrows = (Nq - n0 < 32) ? (Nq - n0) : 32;

  const int w = tid >> 6;
  const int lane = tid & 63;
  const int fm = lane & 15;
  const int quad = lane >> 4;
  const int lrow = lane >> 3;
  const int lchunk = lane & 7;
  const int schunk = lchunk ^ lrow;

  if (tid < 32) {
    m_s[tid] = -1e30f;
    l_s[tid] = 0.f;
  }

  // stage Q (32 rows): one 16B gl_lds per wave, rows w*8 + lrow
  {
    const unsigned short* gq =
        Q + ((size_t)b * Nq + n0 + w * 8 + lrow) * qs + h * 64 + schunk * 8;
    __builtin_amdgcn_global_load_lds((const __attribute__((address_space(1))) void*)gq,
                                     (__attribute__((address_space(3))) void*)(q_s + w * 8 * 64),
                                     16, 0, 0);
  }

  float acc[8] = {0.f, 0.f, 0.f, 0.f, 0.f, 0.f, 0.f, 0.f};

  for (int m0 = 0; m0 < Nk; m0 += 64) {
    const int mc = (Nk - m0 < 64) ? (Nk - m0) : 64;
    __syncthreads();  // prev PV done with v_s/sc
    // stage K (swizzled) + V (linear): rows w*16 + g*8 + lrow
#pragma unroll
    for (int g = 0; g < 2; ++g) {
      const int rg = w * 16 + g * 8;
      const size_t grow = (size_t)b * Nk + m0 + rg + lrow;
      const unsigned short* gk = K + grow * ks + h * 64 + schunk * 8;
      const unsigned short* gv = V + grow * vs + h * 64 + lchunk * 8;
      __builtin_amdgcn_global_load_lds((const __attribute__((address_space(1))) void*)gk,
                                       (__attribute__((address_space(3))) void*)(k_s + rg * 64),
                                       16, 0, 0);
      __builtin_amdgcn_global_load_lds((const __attribute__((address_space(1))) void*)gv,
                                       (__attribute__((address_space(3))) void*)(v_s + rg * 64),
                                       16, 0, 0);
    }
    __syncthreads();  // loads drained (compiler vmcnt(0) before barrier) + visible

    // QK^T MFMA: wave -> row-tile (w&1), col-tiles (w>>1)*2 + {0,1}
    {
      const int rt = w & 1;
      const int arow = (rt << 4) + fm;
      const bf16x8 a0 = *(const bf16x8*)(q_s + (arow << 6) + ((quad ^ (arow & 7)) << 3));
      const bf16x8 a1 = *(const bf16x8*)(q_s + (arow << 6) + (((4 + quad) ^ (arow & 7)) << 3));
      const int ct0 = (w >> 1) << 1;
#pragma unroll
      for (int j = 0; j < 2; ++j) {
        const int brow = ((ct0 + j) << 4) + fm;
        const bf16x8 b0 = *(const bf16x8*)(k_s + (brow << 6) + ((quad ^ (brow & 7)) << 3));
        const bf16x8 b1 = *(const bf16x8*)(k_s + (brow << 6) + (((4 + quad) ^ (brow & 7)) << 3));
        f32x4 sv = (f32x4){0.f, 0.f, 0.f, 0.f};
        sv = __builtin_amdgcn_mfma_f32_16x16x32_bf16(a0, b0, sv, 0, 0, 0);
        sv = __builtin_amdgcn_mfma_f32_16x16x32_bf16(a1, b1, sv, 0, 0, 0);
        const int srow = (rt << 4) + (quad << 2);
        const int scol = ((ct0 + j) << 4) + fm;
#pragma unroll
        for (int reg = 0; reg < 4; ++reg) sc[srow + reg][scol] = sv[reg] * ATT_SCALE;
      }
    }
    __syncthreads();

    // online softmax, all 32 rows in parallel: row = w*8+lrow, 8 cols per lane
    {
      const int r = (w << 3) + lrow;
      const int c0 = lchunk << 3;
      float4 pa = *(const float4*)&sc[r][c0];
      float4 pb = *(const float4*)&sc[r][c0 + 4];
      float vv[8] = {pa.x, pa.y, pa.z, pa.w, pb.x, pb.y, pb.z, pb.w};
      float mx = -1e30f;
#pragma unroll
      for (int e = 0; e < 8; ++e) {
        if (c0 + e >= mc) vv[e] = -1e30f;
        mx = fmaxf(mx, vv[e]);
      }
      mx = fmaxf(mx, __shfl_xor(mx, 1, 64));
      mx = fmaxf(mx, __shfl_xor(mx, 2, 64));
      mx = fmaxf(mx, __shfl_xor(mx, 4, 64));
      const float mo = m_s[r];
      const float mn = fmaxf(mo, mx);
      float sum = 0.f;
#pragma unroll
      for (int e = 0; e < 8; ++e) {
        const float ev = (c0 + e < mc) ? __expf(vv[e] - mn) : 0.f;
        vv[e] = ev;
        sum += ev;
      }
      *(float4*)&sc[r][c0] = (float4){vv[0], vv[1], vv[2], vv[3]};
      *(float4*)&sc[r][c0 + 4] = (float4){vv[4], vv[5], vv[6], vv[7]};
      sum += __shfl_xor(sum, 1, 64);
      sum += __shfl_xor(sum, 2, 64);
      sum += __shfl_xor(sum, 4, 64);
      if (lchunk == 0) {
        const float sca = __expf(mo - mn);
        rs_s[r] = sca;
        l_s[r] = l_s[r] * sca + sum;
        m_s[r] = mn;
      }
    }
    __syncthreads();

    // PV from LDS (full 64 cols; pad cols have p=0, pad V rows are 0)
#pragma unroll
    for (int rr = 0; rr < 8; ++rr) acc[rr] *= rs_s[w + (rr << 2)];
#pragma unroll 4
    for (int m = 0; m < 64; m += 4) {
      float4 p[8];
#pragma unroll
      for (int rr = 0; rr < 8; ++rr) p[rr] = *(const float4*)&sc[w + (rr << 2)][m];
      const float v0 = bf2f(v_s[(m + 0) * 64 + lane]);
      const float v1 = bf2f(v_s[(m + 1) * 64 + lane]);
      const float v2 = bf2f(v_s[(m + 2) * 64 + lane]);
      const float v3 = bf2f(v_s[(m + 3) * 64 + lane]);
#pragma unroll
      for (int rr = 0; rr < 8; ++rr) {
        acc[rr] = fmaf(p[rr].x, v0, acc[rr]);
        acc[rr] = fmaf(p[rr].y, v1, acc[rr]);
        acc[rr] = fmaf(p[rr].z, v2, acc[rr]);
        acc[rr] = fmaf(p[rr].w, v3, acc[rr]);
      }
    }
  }

  // epilogue: O = acc / l  (l_s synced at last softmax barrier)
#pragma unroll
  for (int rr = 0; rr < 8; ++rr) {
    const int r = w + (rr << 2);
    if (r < nrows)
      O[((size_t)b * Nq + n0 + r) * DM + h * 64 + lane] = f2bf(acc[rr] / l_s[r]);
  }
}

// ------------------------------------------------------------------
extern "C" void kernel_launch(void* const* d_in, const int* in_sizes, int n_in, void* d_out,
                              int out_size, void* d_ws, size_t ws_size, hipStream_t stream) {
  const float* local_in = (const float*)d_in[0];
  const float* centers = (const float*)d_in[1];
  const float* scales = (const float*)d_in[2];
  const float* scene_tok = (const float*)d_in[3];
  const float* periods = (const float*)d_in[4];
  const float* read_gate = (const float*)d_in[5];
  const float* write_gate = (const float*)d_in[6];
  const float* ln1w = (const float*)d_in[7];
  const float* ln1b = (const float*)d_in[8];
  const float* ln2w = (const float*)d_in[9];
  const float* ln2b = (const float*)d_in[10];
  const float* Wqkv = (const float*)d_in[11];
  const float* bqkv = (const float*)d_in[12];
  const float* Wp = (const float*)d_in[13];
  const float* bp = (const float*)d_in[14];
  const float* W1 = (const float*)d_in[15];
  const float* b1 = (const float*)d_in[16];
  const float* W2 = (const float*)d_in[17];
  const float* b2 = (const float*)d_in[18];
  const float* rqW = (const float*)d_in[19];
  const float* rqb = (const float*)d_in[20];
  const float* rkW = (const float*)d_in[21];
  const float* rkb = (const float*)d_in[22];
  const float* rvW = (const float*)d_in[23];
  const float* rvb = (const float*)d_in[24];
  const float* roW = (const float*)d_in[25];
  const float* rob = (const float*)d_in[26];
  const float* wqW = (const float*)d_in[27];
  const float* wqb = (const float*)d_in[28];
  const float* wkW = (const float*)d_in[29];
  const float* wkb = (const float*)d_in[30];
  const float* wvW = (const float*)d_in[31];
  const float* wvb = (const float*)d_in[32];
  const float* woW = (const float*)d_in[33];
  const float* wob = (const float*)d_in[34];

  float* out = (float*)d_out;
  float* local = out;                              // (3136, 768) fp32
  float* scene = out + (size_t)ML * DM;            // (16384, 768) fp32

  // workspace layout (bf16 = unsigned short)
  constexpr size_t E_WSLOT = 11796480;             // per-layer weights bf16 [N][K]
  constexpr size_t E_LBF = (size_t)ML_PAD * DM;    // 2457600
  constexpr size_t E_BUF = (size_t)MS * DM;        // 12582912
  unsigned short* wslot = (unsigned short*)d_ws;
  unsigned short* local_bf = wslot + E_WSLOT;
  unsigned short* scene_bf = local_bf + E_LBF;
  unsigned short* bufQ = scene_bf + E_BUF;
  unsigned short* bufKV = bufQ + E_BUF;            // [16384][1536] interleaved K|V
  unsigned short* bufO = bufKV + 2 * E_BUF;
  unsigned short* bufH = bufO + E_BUF;
  float* lcos = (float*)(bufH + E_LBF);
  float* lsin = lcos + BATCH * NLOC * 32;
  float* scos = lsin + BATCH * NLOC * 32;
  float* ssin = scos + NSC * 32;

  const int totOut = (ML + MS) * DM;
  init_out_k<<<(totOut + 255) / 256, 256, 0, stream>>>(local_in, scene_tok, out, local_bf,
                                                       scene_bf);
  rope_local_k<<<(BATCH * NLOC * 32 + 255) / 256, 256, 0, stream>>>(centers, scales, periods,
                                                                    lcos, lsin);
  rope_scene_k<<<(NSC * 32 + 255) / 256, 256, 0, stream>>>(periods, scos, ssin);

  const size_t DD = (size_t)DM * DM;
  const dim3 gS(6, MS / 128);        // scene-M 768-N
  const dim3 gL(6, ML_PAD / 128);    // local-M 768-N
  const dim3 gSKV(12, MS / 128);     // scene-M 1536-N (fused K|V)
  const dim3 gLKV(12, ML_PAD / 128); // local-M 1536-N (fused K|V)
  for (int i = 0; i < NLAYER; ++i) {
    SrcPtrs sp;
    sp.p[0] = Wqkv + (size_t)DM * 3 * DM * i;
    sp.p[1] = Wp + DD * i;
    sp.p[2] = W1 + (size_t)DM * 4 * DM * i;
    sp.p[3] = W2 + (size_t)4 * DM * DM * i;
    sp.p[4] = rqW + DD * i;
    sp.p[5] = rkW + DD * i;
    sp.p[6] = rvW + DD * i;
    sp.p[7] = roW + DD * i;
    sp.p[8] = wqW + DD * i;
    sp.p[9] = wkW + DD * i;
    sp.p[10] = wvW + DD * i;
    sp.p[11] = woW + DD * i;
    wconv_k<<<11520, 256, 0, stream>>>(sp, wslot);

    // ---- read cross-attn: local(49q) <- scene(256kv)
    gemm_mfma<0, 1><<<gL, 256, 0, stream>>>(local_bf, wslot + W_RQ, rqb + DM * i, nullptr, bufQ,
                                            nullptr, nullptr, lcos, lsin, DM, ML, ML_PAD, DM, DM);
    gemm_mfma<0, 2><<<gSKV, 256, 0, stream>>>(scene_bf, wslot + W_RK, rkb + DM * i, rvb + DM * i,
                                              bufKV, nullptr, nullptr, scos, ssin, DM, MS, MS,
                                              2 * DM, DM);
    attn_k<<<dim3(BATCH * NHD * 2), 256, 0, stream>>>(bufQ, DM, bufKV, 2 * DM, bufKV + DM,
                                                      2 * DM, bufO, NLOC, NSC);
    gemm_mfma<2, 0><<<gL, 256, 0, stream>>>(bufO, wslot + W_RO, rob + DM * i, nullptr, local_bf,
                                            local, read_gate + DM * i, nullptr, nullptr, 0, ML,
                                            ML, DM, DM);
    // ---- backend block on local
    ln_k<<<ML / 4, 256, 0, stream>>>(local, ln1w + DM * i, ln1b + DM * i, bufH, ML);
    gemm_mfma<0, 1><<<dim3(18, ML_PAD / 128), 256, 0, stream>>>(bufH, wslot + W_QKV,
                                                                bqkv + 3 * DM * i, nullptr, bufQ,
                                                                nullptr, nullptr, lcos, lsin,
                                                                2 * DM, ML, ML_PAD, 3 * DM, DM);
    attn_k<<<dim3(BATCH * NHD * 2), 256, 0, stream>>>(bufQ, 3 * DM, bufQ + DM, 3 * DM,
                                                      bufQ + 2 * DM, 3 * DM, bufO, NLOC, NLOC);
    gemm_mfma<2, 0><<<gL, 256, 0, stream>>>(bufO, wslot + W_P, bp + DM * i, nullptr, local_bf,
                                            local, nullptr, nullptr, nullptr, 0, ML, ML, DM, DM);
    ln_k<<<ML / 4, 256, 0, stream>>>(local, ln2w + DM * i, ln2b + DM * i, bufH, ML);
    gemm_mfma<1, 0><<<dim3(24, ML_PAD / 128), 256, 0, stream>>>(bufH, wslot + W_1,
                                                                b1 + 4 * DM * i, nullptr, bufO,
                                                                nullptr, nullptr, nullptr,
                                                                nullptr, 0, ML, ML, 4 * DM, DM);
    gemm_mfma<2, 0><<<gL, 256, 0, stream>>>(bufO, wslot + W_2, b2 + DM * i, nullptr, local_bf,
                                            local, nullptr, nullptr, nullptr, 0, ML, ML, DM,
                                            4 * DM);
    // ---- write cross-attn: scene(256q) <- local(49kv)
    gemm_mfma<0, 2><<<gS, 256, 0, stream>>>(scene_bf, wslot + W_WQ, wqb + DM * i, nullptr, bufQ,
                                            nullptr, nullptr, scos, ssin, DM, MS, MS, DM, DM);
    gemm_mfma<0, 1><<<gLKV, 256, 0, stream>>>(local_bf, wslot + W_WK, wkb + DM * i, wvb + DM * i,
                                              bufKV, nullptr, nullptr, lcos, lsin, DM, ML,
                                              ML_PAD, 2 * DM, DM);
    attn_k<<<dim3(BATCH * NHD * 8), 256, 0, stream>>>(bufQ, DM, bufKV, 2 * DM, bufKV + DM,
                                                      2 * DM, bufO, NSC, NLOC);
    gemm_mfma<2, 0><<<gS, 256, 0, stream>>>(bufO, wslot + W_WO, wob + DM * i, nullptr, scene_bf,
                                            scene, write_gate + DM * i, nullptr, nullptr, 0, MS,
                                            MS, DM, DM);
  }
}